// Round 1
// baseline (31857.385 us; speedup 1.0000x reference)
//
#include <hip/hip_runtime.h>
#include <math.h>

// NCA: grid (64,64,64,16), 60 steps of conv3x3(16->128)+relu, dense(128->256)+relu,
// dense(256->16), masked residual update; final softmax over channels 1..10.
#define NB 64
#define NH 64
#define NW 64
#define NC 16
#define NF 128
#define ND 256
#define NSTEP 60
#define GRID_ELEMS (NB*NH*NW*NC)   // 4,194,304 floats = 16 MB
#define NPIX (NB*NH*NW)            // 262,144

// ---------------- init: grid ch0 = input, others 0 ----------------
__global__ void init_grid(const float* __restrict__ inp, float* __restrict__ g) {
    int i = blockIdx.x * 256 + threadIdx.x;
    if (i >= GRID_ELEMS) return;
    int c = i & 15;
    g[i] = (c == 0) ? inp[i >> 4] : 0.0f;
}

// ---------------- fused NCA step ----------------
// One block = 8x8 pixel tile of one image, 256 threads.
// LDS (63744 B static -> 2 blocks/CU):
//   hs  [128][64]   32 KB   (conv output, persists through dense phase)
//   union region (reused conv->dense):
//     conv : gs[16][10][10] (6.4 KB) + cwS[3][16][128] (24 KB)
//     dense: w1S[128][32] (16 KB) + aS[32][64] (8 KB) + w2S[32][16] (2 KB)
__global__ __launch_bounds__(256) void nca_step(
    const float* __restrict__ gin, float* __restrict__ gout,
    const float* __restrict__ cw, const float* __restrict__ cb,
    const float* __restrict__ w1, const float* __restrict__ b1,
    const float* __restrict__ w2, const float* __restrict__ b2)
{
    __shared__ float smem[15936];
    float* const hs  = smem;               // [128][64] f-major, px-minor
    float* const gs  = smem + 8192;        // conv: [16][10][10] c-major
    float* const cwS = smem + 8192 + 1600; // conv: [kx][c][f] for one ky row
    float* const w1S = smem + 8192;        // dense: [128][32] f-major
    float* const aS  = smem + 8192 + 4096; // dense: [32][64] j-major
    float* const w2S = smem + 8192 + 6144; // dense: [32][16]

    const int t  = threadIdx.x;
    const int bi = blockIdx.x;
    const int b  = bi >> 6;
    const int y0 = ((bi >> 3) & 7) << 3;
    const int x0 = (bi & 7) << 3;

    // ---- stage grid tile with halo (zero-pad SAME) ----
    for (int i = t; i < 1600; i += 256) {
        int yy  = i / 160;
        int rem = i - yy * 160;
        int xx  = rem >> 4;
        int c   = rem & 15;
        int gy = y0 + yy - 1, gx = x0 + xx - 1;
        float v = 0.0f;
        if ((unsigned)gy < 64u && (unsigned)gx < 64u)
            v = gin[(((b << 6) + gy) * 64 + gx) * 16 + c];
        gs[c * 100 + yy * 10 + xx] = v;
    }

    // ---- conv 3x3x16 -> 128 + bias + relu ----
    // thread = 8 filters (f0..f0+7) x 4 consecutive pixels (one row segment)
    const int fb  = t & 15;   const int f0  = fb << 3;
    const int pxb = t >> 4;   const int px0 = pxb << 2;
    const int py  = px0 >> 3; const int pxx = px0 & 7;

    float acc[4][8];
    #pragma unroll
    for (int i = 0; i < 4; ++i)
        #pragma unroll
        for (int k = 0; k < 8; ++k) acc[i][k] = 0.0f;

    for (int ky = 0; ky < 3; ++ky) {
        __syncthreads();                       // gs ready (ky=0) / cwS free (ky>0)
        for (int i = t; i < 6144; i += 256) cwS[i] = cw[ky * 6144 + i];
        __syncthreads();
        #pragma unroll
        for (int kx = 0; kx < 3; ++kx) {
            #pragma unroll
            for (int c = 0; c < 16; ++c) {
                float wv[8], gv[4];
                #pragma unroll
                for (int k = 0; k < 8; ++k) wv[k] = cwS[(kx * 16 + c) * 128 + f0 + k];
                #pragma unroll
                for (int i = 0; i < 4; ++i) gv[i] = gs[c * 100 + (py + ky) * 10 + (pxx + kx) + i];
                #pragma unroll
                for (int i = 0; i < 4; ++i)
                    #pragma unroll
                    for (int k = 0; k < 8; ++k) acc[i][k] = fmaf(gv[i], wv[k], acc[i][k]);
            }
        }
    }
    {
        float cbv[8];
        #pragma unroll
        for (int k = 0; k < 8; ++k) cbv[k] = cb[f0 + k];
        #pragma unroll
        for (int k = 0; k < 8; ++k)
            #pragma unroll
            for (int i = 0; i < 4; ++i)
                hs[(f0 + k) * 64 + px0 + i] = fmaxf(acc[i][k] + cbv[k], 0.0f);
    }

    // ---- dense1 (128->256, relu) fused with dense2 (256->16), j-chunks of 32 ----
    const int jb = t & 15;        // dense1: 2 j-columns per thread
    const int cD = t & 15;        // dense2: output channel
    float dacc[4] = {0.f, 0.f, 0.f, 0.f};

    for (int ch = 0; ch < 8; ++ch) {
        const int j0g = ch << 5;
        __syncthreads();                       // prior chunk done / conv regions free
        for (int i = t; i < 4096; i += 256) {
            int f = i >> 5, jj = i & 31;
            w1S[i] = w1[f * 256 + j0g + jj];
        }
        for (int i = t; i < 512; i += 256) w2S[i] = w2[j0g * 16 + i];
        __syncthreads();

        // dense1: a[px][j] = relu(sum_f h*w1 + b1)
        const int jl = jb << 1;
        float a1[4][2];
        #pragma unroll
        for (int i = 0; i < 4; ++i) { a1[i][0] = 0.f; a1[i][1] = 0.f; }
        #pragma unroll 4
        for (int f = 0; f < 128; ++f) {
            float w0  = w1S[f * 32 + jl];
            float w1v = w1S[f * 32 + jl + 1];
            float hv[4];
            #pragma unroll
            for (int i = 0; i < 4; ++i) hv[i] = hs[f * 64 + px0 + i];
            #pragma unroll
            for (int i = 0; i < 4; ++i) {
                a1[i][0] = fmaf(hv[i], w0,  a1[i][0]);
                a1[i][1] = fmaf(hv[i], w1v, a1[i][1]);
            }
        }
        float b1v0 = b1[j0g + jl], b1v1 = b1[j0g + jl + 1];
        #pragma unroll
        for (int i = 0; i < 4; ++i) {
            aS[jl * 64 + px0 + i]       = fmaxf(a1[i][0] + b1v0, 0.0f);
            aS[(jl + 1) * 64 + px0 + i] = fmaxf(a1[i][1] + b1v1, 0.0f);
        }
        __syncthreads();

        // dense2 partial: d[px][c] += a * w2
        #pragma unroll 8
        for (int jj = 0; jj < 32; ++jj) {
            float wv = w2S[jj * 16 + cD];
            float av[4];
            #pragma unroll
            for (int i = 0; i < 4; ++i) av[i] = aS[jj * 64 + px0 + i];
            #pragma unroll
            for (int i = 0; i < 4; ++i) dacc[i] = fmaf(av[i], wv, dacc[i]);
        }
    }

    // ---- masked residual update (ch0 frozen; alive = ch0 > 0.1) ----
    const float b2v = b2[cD];
    #pragma unroll
    for (int i = 0; i < 4; ++i) {
        int px = px0 + i;
        int yW = y0 + (px >> 3), xW = x0 + (px & 7);
        int gidx = (((b << 6) + yW) * 64 + xW) * 16 + cD;
        float gv = gin[gidx];
        float a0 = gin[gidx - cD];             // channel 0 of this pixel
        float nv = gv;
        if (cD != 0 && a0 > 0.1f) nv += dacc[i] + b2v;
        gout[gidx] = nv;
    }
}

// ---------------- final softmax over channels 1..10 ----------------
__global__ void softmax_out(const float* __restrict__ g, float* __restrict__ out) {
    int pix = blockIdx.x * 256 + threadIdx.x;
    if (pix >= NPIX) return;
    const float* gp = g + pix * 16;
    float v[10];
    float m = -1e30f;
    #pragma unroll
    for (int i = 0; i < 10; ++i) { v[i] = gp[1 + i]; m = fmaxf(m, v[i]); }
    float s = 0.f;
    #pragma unroll
    for (int i = 0; i < 10; ++i) { v[i] = __expf(v[i] - m); s += v[i]; }
    float inv = 1.0f / s;
    float* op = out + pix * 10;
    #pragma unroll
    for (int i = 0; i < 10; ++i) op[i] = v[i] * inv;
}

extern "C" void kernel_launch(void* const* d_in, const int* in_sizes, int n_in,
                              void* d_out, int out_size, void* d_ws, size_t ws_size,
                              hipStream_t stream) {
    const float* inp = (const float*)d_in[0];
    const float* cw  = (const float*)d_in[1];
    const float* cb  = (const float*)d_in[2];
    const float* w1  = (const float*)d_in[3];
    const float* b1  = (const float*)d_in[4];
    const float* w2  = (const float*)d_in[5];
    const float* b2  = (const float*)d_in[6];
    float* out = (float*)d_out;

    float* g0 = (float*)d_ws;             // double-buffered grid state
    float* g1 = g0 + GRID_ELEMS;

    init_grid<<<(GRID_ELEMS + 255) / 256, 256, 0, stream>>>(inp, g0);

    float* bufs[2] = { g0, g1 };
    for (int s = 0; s < NSTEP; ++s) {
        nca_step<<<4096, 256, 0, stream>>>(bufs[s & 1], bufs[(s + 1) & 1],
                                           cw, cb, w1, b1, w2, b2);
    }
    // NSTEP=60 even -> final state in g0
    softmax_out<<<(NPIX + 255) / 256, 256, 0, stream>>>(g0, out);
}

// Round 4
// 17574.734 us; speedup vs baseline: 1.8127x; 1.8127x over previous
//
#include <hip/hip_runtime.h>
#include <math.h>

typedef _Float16 f16;
typedef f16  f16x8 __attribute__((ext_vector_type(8)));
typedef float f32x4 __attribute__((ext_vector_type(4)));

#define NB 64
#define NC 16
#define NF 128
#define ND 256
#define NSTEP 60
#define GRID_ELEMS (NB*64*64*NC)   // 16 MB fp32
#define NPIX (NB*64*64)

// ---------------- init: grid ch0 = input, others 0 ----------------
__global__ void init_grid(const float* __restrict__ inp, float* __restrict__ g) {
    int i = blockIdx.x * 256 + threadIdx.x;
    if (i >= GRID_ELEMS) return;
    int c = i & 15;
    g[i] = (c == 0) ? inp[i >> 4] : 0.0f;
}

// ---------------- fused NCA step: R1 structure, dense1 -> MFMA probe ----------------
// Block = 8x8 pixel tile, 256 threads = 4 waves.
// LDS: convU[7744]f32 { conv: gs[1600]+cwS[6144] | dense: aS[2048]+w2S[512] }
//      hsH/hsL[64px][136f] split-f16 conv output for MFMA B-fragments.
__global__ __launch_bounds__(256, 2) void nca_step(
    const float* __restrict__ gin, float* __restrict__ gout,
    const float* __restrict__ cw, const float* __restrict__ cb,
    const float* __restrict__ w1, const float* __restrict__ b1,
    const float* __restrict__ w2, const float* __restrict__ b2)
{
    __shared__ float convU[7744];
    __shared__ f16 hsH[8704];
    __shared__ f16 hsL[8704];
    float* const gs  = convU;          // [16][10][10] c-major
    float* const cwS = convU + 1600;   // [kx][c][f] one ky row
    float* const aS  = convU;          // dense: [32][64] j-major
    float* const w2S = convU + 2048;   // dense: [32][16]

    const int t    = threadIdx.x;
    const int w    = t >> 6;
    const int lane = t & 63;
    const int q    = lane >> 4;
    const int l16  = lane & 15;

    const int bi = blockIdx.x;
    const int b  = bi >> 6;
    const int y0 = ((bi >> 3) & 7) << 3;
    const int x0 = (bi & 7) << 3;

    // ---- stage grid tile with halo (zero-pad SAME) — R1 verbatim ----
    for (int i = t; i < 1600; i += 256) {
        int yy  = i / 160;
        int rem = i - yy * 160;
        int xx  = rem >> 4;
        int c   = rem & 15;
        int gy = y0 + yy - 1, gx = x0 + xx - 1;
        float v = 0.0f;
        if ((unsigned)gy < 64u && (unsigned)gx < 64u)
            v = gin[(((b << 6) + gy) * 64 + gx) * 16 + c];
        gs[c * 100 + yy * 10 + xx] = v;
    }

    // ---- conv 3x3x16 -> 128 + bias + relu — R1 verbatim (VALU) ----
    const int fb  = t & 15;   const int f0  = fb << 3;
    const int pxb = t >> 4;   const int px0 = pxb << 2;
    const int py  = px0 >> 3; const int pxx = px0 & 7;

    float acc[4][8];
    #pragma unroll
    for (int i = 0; i < 4; ++i)
        #pragma unroll
        for (int k = 0; k < 8; ++k) acc[i][k] = 0.0f;

    for (int ky = 0; ky < 3; ++ky) {
        __syncthreads();
        for (int i = t; i < 6144; i += 256) cwS[i] = cw[ky * 6144 + i];
        __syncthreads();
        #pragma unroll
        for (int kx = 0; kx < 3; ++kx) {
            #pragma unroll
            for (int c = 0; c < 16; ++c) {
                float wv[8], gv[4];
                #pragma unroll
                for (int k = 0; k < 8; ++k) wv[k] = cwS[(kx * 16 + c) * 128 + f0 + k];
                #pragma unroll
                for (int i = 0; i < 4; ++i) gv[i] = gs[c * 100 + (py + ky) * 10 + (pxx + kx) + i];
                #pragma unroll
                for (int i = 0; i < 4; ++i)
                    #pragma unroll
                    for (int k = 0; k < 8; ++k) acc[i][k] = fmaf(gv[i], wv[k], acc[i][k]);
            }
        }
    }

    // bias + relu + split-f16 store to hsH/hsL[px][f] (pad 136) for MFMA B
    {
        float cbv[8];
        #pragma unroll
        for (int k = 0; k < 8; ++k) cbv[k] = cb[f0 + k];
        #pragma unroll
        for (int i = 0; i < 4; ++i) {
            f16x8 ph, pl;
            #pragma unroll
            for (int k = 0; k < 8; ++k) {
                float v = fmaxf(acc[i][k] + cbv[k], 0.0f);
                f16 hv = (f16)v;
                ph[k] = hv;
                pl[k] = (f16)(v - (float)hv);
            }
            *(f16x8*)(hsH + (px0 + i) * 136 + f0) = ph;
            *(f16x8*)(hsL + (px0 + i) * 136 + f0) = pl;
        }
    }
    __syncthreads();   // hs published; gs/cwS region dead -> aS/w2S

    // ---- dense1 via split-f16 MFMA; dense2 VALU (R1) ----
    // wave w: j-tile jt2w = w&1 (16 j), pixel groups {w>>1, (w>>1)+2} (16 px each)
    const int jt2w = w & 1;
    const int pgA  = w >> 1;
    const int cD = t & 15;
    float dacc[4] = {0.f, 0.f, 0.f, 0.f};

    for (int ch = 0; ch < 8; ++ch) {
        __syncthreads();                     // aS/w2S free (prev chunk consumed)
        for (int i = t; i < 512; i += 256) w2S[i] = w2[ch * 512 + i];

        // A-fragments: w1T[j][f] built on the fly from global fp32 w1 (split hi/lo)
        const int jg = ch * 32 + jt2w * 16 + l16;
        f16x8 aH[4], aL[4];
        #pragma unroll
        for (int kc = 0; kc < 4; ++kc)
            #pragma unroll
            for (int jj = 0; jj < 8; ++jj) {
                float v = w1[(kc * 32 + q * 8 + jj) * 256 + jg];
                f16 hv = (f16)v;
                aH[kc][jj] = hv;
                aL[kc][jj] = (f16)(v - (float)hv);
            }
        float b1r[4];
        #pragma unroll
        for (int r = 0; r < 4; ++r) b1r[r] = b1[ch * 32 + jt2w * 16 + q * 4 + r];

        #pragma unroll
        for (int pgi = 0; pgi < 2; ++pgi) {
            const int pg = pgA + pgi * 2;
            f32x4 a1;
            a1.x = b1r[0]; a1.y = b1r[1]; a1.z = b1r[2]; a1.w = b1r[3];
            #pragma unroll
            for (int kc = 0; kc < 4; ++kc) {
                f16x8 bh = *(const f16x8*)(hsH + (pg * 16 + l16) * 136 + kc * 32 + q * 8);
                f16x8 bl = *(const f16x8*)(hsL + (pg * 16 + l16) * 136 + kc * 32 + q * 8);
                a1 = __builtin_amdgcn_mfma_f32_16x16x32_f16(aH[kc], bh, a1, 0, 0, 0);
                a1 = __builtin_amdgcn_mfma_f32_16x16x32_f16(aH[kc], bl, a1, 0, 0, 0);
                a1 = __builtin_amdgcn_mfma_f32_16x16x32_f16(aL[kc], bh, a1, 0, 0, 0);
            }
            // D: rows j32 = jt2w*16 + q*4 + r, col px = pg*16 + l16 -> aS[j32][px]
            aS[(jt2w * 16 + q * 4 + 0) * 64 + pg * 16 + l16] = fmaxf(a1.x, 0.0f);
            aS[(jt2w * 16 + q * 4 + 1) * 64 + pg * 16 + l16] = fmaxf(a1.y, 0.0f);
            aS[(jt2w * 16 + q * 4 + 2) * 64 + pg * 16 + l16] = fmaxf(a1.z, 0.0f);
            aS[(jt2w * 16 + q * 4 + 3) * 64 + pg * 16 + l16] = fmaxf(a1.w, 0.0f);
        }
        __syncthreads();                     // aS/w2S ready

        // dense2 partial (R1 verbatim): d[px][c] += a * w2
        #pragma unroll 8
        for (int jj = 0; jj < 32; ++jj) {
            float wv = w2S[jj * 16 + cD];
            float av[4];
            #pragma unroll
            for (int i = 0; i < 4; ++i) av[i] = aS[jj * 64 + px0 + i];
            #pragma unroll
            for (int i = 0; i < 4; ++i) dacc[i] = fmaf(av[i], wv, dacc[i]);
        }
    }

    // ---- masked residual update — R1 verbatim ----
    const float b2v = b2[cD];
    #pragma unroll
    for (int i = 0; i < 4; ++i) {
        int px = px0 + i;
        int yW = y0 + (px >> 3), xW = x0 + (px & 7);
        int gidx = (((b << 6) + yW) * 64 + xW) * 16 + cD;
        float gv = gin[gidx];
        float a0 = gin[gidx - cD];
        float nv = gv;
        if (cD != 0 && a0 > 0.1f) nv += dacc[i] + b2v;
        gout[gidx] = nv;
    }
}

// ---------------- final softmax over channels 1..10 — R1 verbatim ----------------
__global__ void softmax_out(const float* __restrict__ g, float* __restrict__ out) {
    int pix = blockIdx.x * 256 + threadIdx.x;
    if (pix >= NPIX) return;
    const float* gp = g + (size_t)pix * 16;
    float v[10];
    float m = -1e30f;
    #pragma unroll
    for (int i = 0; i < 10; ++i) { v[i] = gp[1 + i]; m = fmaxf(m, v[i]); }
    float s = 0.f;
    #pragma unroll
    for (int i = 0; i < 10; ++i) { v[i] = __expf(v[i] - m); s += v[i]; }
    float inv = 1.0f / s;
    float* op = out + (size_t)pix * 10;
    #pragma unroll
    for (int i = 0; i < 10; ++i) op[i] = v[i] * inv;
}

extern "C" void kernel_launch(void* const* d_in, const int* in_sizes, int n_in,
                              void* d_out, int out_size, void* d_ws, size_t ws_size,
                              hipStream_t stream) {
    const float* inp = (const float*)d_in[0];
    const float* cw  = (const float*)d_in[1];
    const float* cb  = (const float*)d_in[2];
    const float* w1  = (const float*)d_in[3];
    const float* b1  = (const float*)d_in[4];
    const float* w2  = (const float*)d_in[5];
    const float* b2  = (const float*)d_in[6];
    float* out = (float*)d_out;

    float* g0 = (float*)d_ws;             // proven 32 MB in round 1
    float* g1 = g0 + GRID_ELEMS;

    init_grid<<<(GRID_ELEMS + 255) / 256, 256, 0, stream>>>(inp, g0);

    float* bufs[2] = { g0, g1 };
    for (int s = 0; s < NSTEP; ++s) {
        nca_step<<<4096, 256, 0, stream>>>(bufs[s & 1], bufs[(s + 1) & 1],
                                           cw, cb, w1, b1, w2, b2);
    }
    softmax_out<<<(NPIX + 255) / 256, 256, 0, stream>>>(g0, out);
}

// Round 5
// 6425.026 us; speedup vs baseline: 4.9583x; 2.7354x over previous
//
#include <hip/hip_runtime.h>
#include <math.h>

typedef _Float16 f16;
typedef f16  f16x8 __attribute__((ext_vector_type(8)));
typedef f16  f16x4 __attribute__((ext_vector_type(4)));
typedef float f32x4 __attribute__((ext_vector_type(4)));

#define NB 64
#define NC 16
#define NF 128
#define ND 256
#define NSTEP 60
#define GRID_ELEMS (NB*64*64*NC)   // 16 MB fp32
#define NPIX (NB*64*64)

#define KCONV 160                  // 9 taps * 16ch padded to 10 taps

// weight buffer layout (f16 elements) inside d_out scratch region
#define OFF_CWH 0            // [128][160]
#define OFF_CWL 20480
#define OFF_W1H 40960        // [256][128]
#define OFF_W1L 73728
#define OFF_W2H 106496       // [16][256]
#define OFF_W2L 110592

// ---------------- init: grid ch0 = input, others 0 ----------------
__global__ void init_grid(const float* __restrict__ inp, float* __restrict__ g) {
    int i = blockIdx.x * 256 + threadIdx.x;
    if (i >= GRID_ELEMS) return;
    int c = i & 15;
    g[i] = (c == 0) ? inp[i >> 4] : 0.0f;
}

// ---------------- prep: split-f16 transposed weights ----------------
__global__ void prep_weights(const float* __restrict__ cw, const float* __restrict__ w1,
                             const float* __restrict__ w2, f16* __restrict__ wb) {
    int i = blockIdx.x * 256 + threadIdx.x;   // 57344 threads exactly
    float v; int hOff, lOff, idx;
    if (i < 20480) {                          // cwT[f][k], k = tap*16+c (tap9 zero)
        int f = i / 160, k = i - f * 160;
        v = (k < 144) ? cw[k * 128 + f] : 0.0f;
        hOff = OFF_CWH; lOff = OFF_CWL; idx = i;
    } else if (i < 20480 + 32768) {           // w1T[j][f]
        int r = i - 20480;
        int j = r >> 7, f = r & 127;
        v = w1[f * 256 + j];
        hOff = OFF_W1H; lOff = OFF_W1L; idx = r;
    } else {                                  // w2T[c][j]
        int r = i - 20480 - 32768;
        int c = r >> 8, j = r & 255;
        v = w2[j * 16 + c];
        hOff = OFF_W2H; lOff = OFF_W2L; idx = r;
    }
    f16 hi = (f16)v;
    f16 lo = (f16)(v - (float)hi);
    wb[hOff + idx] = hi;
    wb[lOff + idx] = lo;
}

// ---------------- fused NCA step (split-f16 MFMA, fp32-equivalent) ----------------
// Block = 8x16 px tile, 256 threads = 4 waves. Operand-swapped matmuls:
// D'[out][px] = W[out][k] * X[k][px]. Every operand split hi+lo f16;
// AhBh + AhBl + AlBh accumulated fp32.
// Dense j-dim split across waves -> per-wave dacc PARTIALS reduced through LDS
// at the end (this was the R2/R3 bug: partials were written directly).
__global__ __launch_bounds__(256, 2) void nca_step(
    const float* __restrict__ gin, float* __restrict__ gout,
    const f16* __restrict__ wb,
    const float* __restrict__ cb, const float* __restrict__ b1, const float* __restrict__ b2)
{
    // LDS: hsH/hsL [128px][136] (2*34816 B) + union{ haloH/L (11520 B) | aScrH/L (10240 B) }
    // redF (32 KB fp32) overlays the hs region after dense loops complete.
    __shared__ f16 smem[40576];              // 81152 B -> 2 blocks/CU
    f16* const hsH  = smem;                  // 17408 elems
    f16* const hsL  = smem + 17408;
    f16* const un   = smem + 34816;          // union region (5760 elems)
    f16* const haloH = un;                   // [10*18][16]
    f16* const haloL = un + 2880;
    f16* const aScrH = un;                   // [4w*16px][40]
    f16* const aScrL = un + 2560;
    float* const redF = (float*)smem;        // [4][128px][16c] fp32 = 32768 B

    const int t    = threadIdx.x;
    const int w    = t >> 6;
    const int lane = t & 63;
    const int q    = lane >> 4;
    const int l16  = lane & 15;

    const int bi = blockIdx.x;
    const int b  = bi >> 5;
    const int tl = bi & 31;
    const int y0 = (tl >> 2) << 3;
    const int x0 = (tl & 3) << 4;

    const float* gb  = gin  + (size_t)b * 64 * 64 * 16;
    float*       gob = gout + (size_t)b * 64 * 64 * 16;

    // ---- stage halo (split f16), zero-pad SAME ----
    for (int i = t; i < 2880; i += 256) {
        int c  = i & 15;
        int xy = i >> 4;
        int xx = xy % 18;
        int yy = xy / 18;
        int gy = y0 + yy - 1, gx = x0 + xx - 1;
        float v = 0.0f;
        if ((unsigned)gy < 64u && (unsigned)gx < 64u)
            v = gb[(gy * 64 + gx) * 16 + c];
        f16 hi = (f16)v;
        haloH[i] = hi;
        haloL[i] = (f16)(v - (float)hi);
    }
    __syncthreads();

    // ================= conv 3x3x16 -> 128, bias, relu =================
    const int fbase = w << 5;                // wave owns 32 filters
    f16x8 cAh[2][5], cAl[2][5];
    #pragma unroll
    for (int ft = 0; ft < 2; ++ft)
        #pragma unroll
        for (int kc = 0; kc < 5; ++kc) {
            size_t idx = (size_t)(fbase + ft * 16 + l16) * KCONV + kc * 32 + q * 8;
            cAh[ft][kc] = *(const f16x8*)(wb + OFF_CWH + idx);
            cAl[ft][kc] = *(const f16x8*)(wb + OFF_CWL + idx);
        }

    f32x4 acc[2][8];
    #pragma unroll
    for (int ft = 0; ft < 2; ++ft) {
        f32x4 bias;
        bias.x = cb[fbase + ft * 16 + q * 4 + 0];
        bias.y = cb[fbase + ft * 16 + q * 4 + 1];
        bias.z = cb[fbase + ft * 16 + q * 4 + 2];
        bias.w = cb[fbase + ft * 16 + q * 4 + 3];
        #pragma unroll
        for (int p = 0; p < 8; ++p) acc[ft][p] = bias;
    }

    #pragma unroll
    for (int kc = 0; kc < 5; ++kc) {
        int tap = kc * 2 + (q >> 1);
        if (tap > 8) tap = 8;                // k>=144: weights (hi&lo) are zero
        int dy = tap / 3, dx = tap - dy * 3;
        int boff = dy * 288 + (l16 + dx) * 16 + (q & 1) * 8;
        #pragma unroll
        for (int p = 0; p < 8; ++p) {
            f16x8 bh = *(const f16x8*)(haloH + boff + p * 288);
            f16x8 bl = *(const f16x8*)(haloL + boff + p * 288);
            #pragma unroll
            for (int ft = 0; ft < 2; ++ft) {
                acc[ft][p] = __builtin_amdgcn_mfma_f32_16x16x32_f16(cAh[ft][kc], bh, acc[ft][p], 0, 0, 0);
                acc[ft][p] = __builtin_amdgcn_mfma_f32_16x16x32_f16(cAh[ft][kc], bl, acc[ft][p], 0, 0, 0);
                acc[ft][p] = __builtin_amdgcn_mfma_f32_16x16x32_f16(cAl[ft][kc], bh, acc[ft][p], 0, 0, 0);
            }
        }
    }

    // relu in fp32, split to hi/lo, write hs[px][f] (b64 packed)
    #pragma unroll
    for (int ft = 0; ft < 2; ++ft)
        #pragma unroll
        for (int p = 0; p < 8; ++p) {
            f32x4 a = acc[ft][p];
            float v0 = fmaxf(a.x, 0.0f), v1 = fmaxf(a.y, 0.0f);
            float v2 = fmaxf(a.z, 0.0f), v3 = fmaxf(a.w, 0.0f);
            f16x4 ph, pl;
            ph.x = (f16)v0; pl.x = (f16)(v0 - (float)ph.x);
            ph.y = (f16)v1; pl.y = (f16)(v1 - (float)ph.y);
            ph.z = (f16)v2; pl.z = (f16)(v2 - (float)ph.z);
            ph.w = (f16)v3; pl.w = (f16)(v3 - (float)ph.w);
            int o = (p * 16 + l16) * 136 + fbase + ft * 16 + q * 4;
            *(f16x4*)(hsH + o) = ph;
            *(f16x4*)(hsL + o) = pl;
        }
    __syncthreads();   // hs published; halo region now dead -> aScr

    // ============ dense1 (128->256, relu) fused w/ dense2 (256->16) ============
    const int jbase = w << 6;                // wave owns 64 j-columns (2 chunks of 32)

    f16x8 w2fh[2], w2fl[2];
    #pragma unroll
    for (int jp = 0; jp < 2; ++jp) {
        size_t o = (size_t)l16 * 256 + jbase + jp * 32 + q * 8;
        w2fh[jp] = *(const f16x8*)(wb + OFF_W2H + o);
        w2fl[jp] = *(const f16x8*)(wb + OFF_W2L + o);
    }

    f32x4 dacc[8];   // PARTIAL over this wave's 64 j (no bias here!)
    #pragma unroll
    for (int p = 0; p < 8; ++p) { dacc[p].x = 0.f; dacc[p].y = 0.f; dacc[p].z = 0.f; dacc[p].w = 0.f; }

    f16* const myScrH = aScrH + (w * 16 + l16) * 40;
    f16* const myScrL = aScrL + (w * 16 + l16) * 40;

    for (int jp = 0; jp < 2; ++jp) {
        f16x8 dAh[2][4], dAl[2][4];
        #pragma unroll
        for (int jt2 = 0; jt2 < 2; ++jt2)
            #pragma unroll
            for (int kc = 0; kc < 4; ++kc) {
                size_t idx = (size_t)(jbase + jp * 32 + jt2 * 16 + l16) * 128 + kc * 32 + q * 8;
                dAh[jt2][kc] = *(const f16x8*)(wb + OFF_W1H + idx);
                dAl[jt2][kc] = *(const f16x8*)(wb + OFF_W1L + idx);
            }
        float b1v[2][4];
        #pragma unroll
        for (int jt2 = 0; jt2 < 2; ++jt2)
            #pragma unroll
            for (int r = 0; r < 4; ++r)
                b1v[jt2][r] = b1[jbase + jp * 32 + jt2 * 16 + q * 4 + r];

        for (int p = 0; p < 8; ++p) {
            f16x8 hBh[4], hBl[4];
            #pragma unroll
            for (int kc = 0; kc < 4; ++kc) {
                int o = (p * 16 + l16) * 136 + kc * 32 + q * 8;
                hBh[kc] = *(const f16x8*)(hsH + o);
                hBl[kc] = *(const f16x8*)(hsL + o);
            }
            #pragma unroll
            for (int jt2 = 0; jt2 < 2; ++jt2) {
                f32x4 a1;
                a1.x = b1v[jt2][0]; a1.y = b1v[jt2][1];
                a1.z = b1v[jt2][2]; a1.w = b1v[jt2][3];
                #pragma unroll
                for (int kc = 0; kc < 4; ++kc) {
                    a1 = __builtin_amdgcn_mfma_f32_16x16x32_f16(dAh[jt2][kc], hBh[kc], a1, 0, 0, 0);
                    a1 = __builtin_amdgcn_mfma_f32_16x16x32_f16(dAh[jt2][kc], hBl[kc], a1, 0, 0, 0);
                    a1 = __builtin_amdgcn_mfma_f32_16x16x32_f16(dAl[jt2][kc], hBh[kc], a1, 0, 0, 0);
                }
                float v0 = fmaxf(a1.x, 0.0f), v1 = fmaxf(a1.y, 0.0f);
                float v2 = fmaxf(a1.z, 0.0f), v3 = fmaxf(a1.w, 0.0f);
                f16x4 ph, pl;
                ph.x = (f16)v0; pl.x = (f16)(v0 - (float)ph.x);
                ph.y = (f16)v1; pl.y = (f16)(v1 - (float)ph.y);
                ph.z = (f16)v2; pl.z = (f16)(v2 - (float)ph.z);
                ph.w = (f16)v3; pl.w = (f16)(v3 - (float)ph.w);
                // D rows j32 = jt2*16+q*4+r, col px=l16 -> scratch[px][j32]
                *(f16x4*)(myScrH + jt2 * 16 + q * 4) = ph;
                *(f16x4*)(myScrL + jt2 * 16 + q * 4) = pl;
            }
            // in-wave transpose readback: A-op [m=px=l16][k=q*8..]
            f16x8 afh = *(const f16x8*)(myScrH + q * 8);
            f16x8 afl = *(const f16x8*)(myScrL + q * 8);
            dacc[p] = __builtin_amdgcn_mfma_f32_16x16x32_f16(afh, w2fh[jp], dacc[p], 0, 0, 0);
            dacc[p] = __builtin_amdgcn_mfma_f32_16x16x32_f16(afh, w2fl[jp], dacc[p], 0, 0, 0);
            dacc[p] = __builtin_amdgcn_mfma_f32_16x16x32_f16(afl, w2fh[jp], dacc[p], 0, 0, 0);
        }
    }

    // ---- cross-wave reduction of dense2 partials (THE R2/R3 FIX) ----
    __syncthreads();                         // all hs reads done -> redF may overwrite
    #pragma unroll
    for (int p = 0; p < 8; ++p)
        #pragma unroll
        for (int r = 0; r < 4; ++r) {
            int px = p * 16 + q * 4 + r;     // D row -> pixel, col l16 -> channel
            redF[w * 2048 + px * 16 + l16] = dacc[p][r];
        }
    __syncthreads();

    // thread t handles px = t>>1, channels c0..c0+7 ; masked residual update
    {
        const int px = t >> 1;
        const int c0 = (t & 1) * 8;
        const int yy = px >> 4, xx = px & 15;
        const size_t pixb = ((size_t)(y0 + yy) * 64 + (x0 + xx)) * 16;
        const float a0 = gb[pixb];           // exact fp32 ch0
        const bool alive = (a0 > 0.1f);
        float sum[8];
        #pragma unroll
        for (int h = 0; h < 2; ++h) {
            f32x4 v0 = *(const f32x4*)(redF +        px * 16 + c0 + h * 4);
            f32x4 v1 = *(const f32x4*)(redF + 2048 + px * 16 + c0 + h * 4);
            f32x4 v2 = *(const f32x4*)(redF + 4096 + px * 16 + c0 + h * 4);
            f32x4 v3 = *(const f32x4*)(redF + 6144 + px * 16 + c0 + h * 4);
            f32x4 sv = v0 + v1 + v2 + v3;
            sum[h * 4 + 0] = sv.x; sum[h * 4 + 1] = sv.y;
            sum[h * 4 + 2] = sv.z; sum[h * 4 + 3] = sv.w;
        }
        #pragma unroll
        for (int i = 0; i < 8; ++i) {
            int c = c0 + i;
            float gv = gb[pixb + c];
            float nv = gv;
            if (alive && c != 0) nv += sum[i] + b2[c];
            gob[pixb + c] = nv;
        }
    }
}

// ---------------- final softmax over channels 1..10 ----------------
__global__ void softmax_out(const float* __restrict__ g, float* __restrict__ out) {
    int pix = blockIdx.x * 256 + threadIdx.x;
    if (pix >= NPIX) return;
    const float* gp = g + (size_t)pix * 16;
    float v[10];
    float m = -1e30f;
    #pragma unroll
    for (int i = 0; i < 10; ++i) { v[i] = gp[1 + i]; m = fmaxf(m, v[i]); }
    float s = 0.f;
    #pragma unroll
    for (int i = 0; i < 10; ++i) { v[i] = __expf(v[i] - m); s += v[i]; }
    float inv = 1.0f / s;
    float* op = out + (size_t)pix * 10;
    #pragma unroll
    for (int i = 0; i < 10; ++i) op[i] = v[i] * inv;
}

extern "C" void kernel_launch(void* const* d_in, const int* in_sizes, int n_in,
                              void* d_out, int out_size, void* d_ws, size_t ws_size,
                              hipStream_t stream) {
    const float* inp = (const float*)d_in[0];
    const float* cw  = (const float*)d_in[1];
    const float* cb  = (const float*)d_in[2];
    const float* w1  = (const float*)d_in[3];
    const float* b1  = (const float*)d_in[4];
    const float* w2  = (const float*)d_in[5];
    const float* b2  = (const float*)d_in[6];
    float* out = (float*)d_out;

    // grid double-buffer in d_ws (32 MB, proven in rounds 1/4)
    float* g0 = (float*)d_ws;
    float* g1 = g0 + GRID_ELEMS;
    // split-f16 weights in d_out scratch (229 KB of 10.48 MB; softmax overwrites at end)
    f16* wb = (f16*)d_out;

    prep_weights<<<224, 256, 0, stream>>>(cw, w1, w2, wb);
    init_grid<<<(GRID_ELEMS + 255) / 256, 256, 0, stream>>>(inp, g0);

    float* bufs[2] = { g0, g1 };
    for (int s = 0; s < NSTEP; ++s) {
        nca_step<<<2048, 256, 0, stream>>>(bufs[s & 1], bufs[(s + 1) & 1],
                                           wb, cb, b1, b2);
    }
    // NSTEP=60 even -> final state in g0
    softmax_out<<<(NPIX + 255) / 256, 256, 0, stream>>>(g0, out);
}